// Round 11
// baseline (357.791 us; speedup 1.0000x reference)
//
#include <hip/hip_runtime.h>
#include <hip/hip_fp16.h>

// Polarisation solver v11: 782-block build (chunk 4096) with LDS bucket-sorted
// staging; per-bucket raw totals via global atomics (second scan set deleted);
// wave-level scans everywhere; sort fuses E0+mu0; atomic-free row-gather Jacobi.
// raw record (16B) = {dst|(localrow<<20), c1 f32, wx|wy f16x2, wz|g f16x2}.
// sorted record (12B) = {dst|(lr<<20), c1|wx f16x2, wy|wz f16x2}.
// Dummy pad records are all-zero (c1==0 flags them).

static constexpr float INV_B  = 1.0f / 0.52917721067f;            // 1/BOHR
static constexpr float INV_B3 = INV_B * INV_B * INV_B;            // 1/BOHR^3
static constexpr float DM = 0.39f;                                 // DAMP_MUTUAL
static constexpr float DF = 0.7f;                                  // DAMP_FIELD
static constexpr int   NITER = 7;
#define SCAN_B 1024
#define STAGE 2048
#define BUILD_T 512
#define MAXBUCK 512

__device__ inline unsigned packh2(float a, float b) {
    return (unsigned)__half_as_ushort(__float2half_rn(a)) |
           ((unsigned)__half_as_ushort(__float2half_rn(b)) << 16);
}
__device__ inline float unph_lo(unsigned u) {
    return __half2float(__ushort_as_half((unsigned short)(u & 0xFFFFu)));
}
__device__ inline float unph_hi(unsigned u) {
    return __half2float(__ushort_as_half((unsigned short)(u >> 16)));
}

// ---- build: per-(block,bucket) padded histogram + per-bucket raw totals ----

__global__ void bhist_kernel(const int* __restrict__ esrc, int* __restrict__ braw,
                             int* __restrict__ hpad, int E, int nbuck, int nblk, int chunk)
{
    __shared__ int cnt[MAXBUCK];
    int tid = threadIdx.x, blk = blockIdx.x;
    for (int b = tid; b < nbuck; b += blockDim.x) cnt[b] = 0;
    __syncthreads();
    int lo = blk * chunk, hi = min(E, lo + chunk);
    for (int i = lo + tid; i < hi; i += blockDim.x)
        atomicAdd(&cnt[esrc[i] >> 8], 1);
    __syncthreads();
    for (int b = tid; b < nbuck; b += blockDim.x) {
        int c = cnt[b];
        hpad[b * nblk + blk] = (c + 7) & ~7;       // 128B-aligned runs
        if (c) atomicAdd(&braw[b], c);             // per-bucket tight totals
    }
}

// ---------------- 2-level exclusive scan (width 1024) ----------------

__global__ void scan1_kernel(const int* __restrict__ in, int* __restrict__ excl,
                             int* __restrict__ blocksum, int n)
{
    __shared__ int sh[SCAN_B];
    int tid = threadIdx.x;
    int i = blockIdx.x * SCAN_B + tid;
    int v = (i < n) ? in[i] : 0;
    sh[tid] = v;
    __syncthreads();
    for (int off = 1; off < SCAN_B; off <<= 1) {
        int t = (tid >= off) ? sh[tid - off] : 0;
        __syncthreads();
        sh[tid] += t;
        __syncthreads();
    }
    if (i < n) excl[i] = sh[tid] - v;
    if (tid == SCAN_B - 1) blocksum[blockIdx.x] = sh[tid];
}

__global__ void scan2_kernel(int* __restrict__ blocksum, int nb)
{
    __shared__ int sh[1024];
    int tid = threadIdx.x;
    int v = (tid < nb) ? blocksum[tid] : 0;
    sh[tid] = v;
    __syncthreads();
    for (int off = 1; off < 1024; off <<= 1) {
        int t = (tid >= off) ? sh[tid - off] : 0;
        __syncthreads();
        sh[tid] += t;
        __syncthreads();
    }
    if (tid < nb) blocksum[tid] = sh[tid] - v;
}

__global__ void scan3_kernel(int* __restrict__ excl, const int* __restrict__ blocksum, int n)
{
    int i = blockIdx.x * SCAN_B + threadIdx.x;
    if (i < n) excl[i] += blocksum[blockIdx.x];
}

// ---- bucket pointers (padded) + tight starts from braw scan, one block ----

__global__ void bktptr_kernel(const int* __restrict__ hoffpad, const int* __restrict__ hpad,
                              const int* __restrict__ braw,
                              int* __restrict__ bktptr, int* __restrict__ tight,
                              int* __restrict__ rowptr,
                              int nbuck, int nblk, int nScan, int N, int E)
{
    __shared__ int wsum[8];
    int tid = threadIdx.x;                          // 512 threads
    int lane = tid & 63, wav = tid >> 6;
    if (tid < nbuck) bktptr[tid] = hoffpad[tid * nblk];
    if (tid == 0) {
        bktptr[nbuck] = hoffpad[nScan - 1] + hpad[nScan - 1];
        if (rowptr) rowptr[N] = E;
    }
    int v = (tid < nbuck) ? braw[tid] : 0;
    int x = v;
    #pragma unroll
    for (int off = 1; off < 64; off <<= 1) {
        int t = __shfl_up(x, off);
        if (lane >= off) x += t;
    }
    if (lane == 63) wsum[wav] = x;
    __syncthreads();
    if (tid < 8) {
        int w = wsum[tid];
        #pragma unroll
        for (int off = 1; off < 8; off <<= 1) {
            int t = __shfl_up(w, off, 8);
            if (tid >= off) w += t;
        }
        wsum[tid] = w;
    }
    __syncthreads();
    int base = (wav > 0) ? wsum[wav - 1] : 0;
    if (tid < nbuck) tight[tid] = x + base - v;     // exclusive prefix of braw
}

// ---- build: sequential reads, LDS bucket-sorted staging, coalesced dump ----
// matvec term: t = c1*mu_d - (w.mu_d)*w, w = sqrt(3*l5m*inv_r5)*vec_ij.
// E0 term: g*w with g = l3f*q_d*inv_r3 / sw.

__global__ __launch_bounds__(BUILD_T)
void build_kernel(const int* __restrict__ esrc, const int* __restrict__ edst,
                  const float* __restrict__ dist, const float* __restrict__ vec,
                  const float* __restrict__ pol, const float* __restrict__ chg,
                  const int* __restrict__ hoffpad, const int* __restrict__ hpad,
                  uint4* __restrict__ recs, int E, int nbuck, int nblk, int chunk)
{
    __shared__ uint4 stg[STAGE];                    // 32 KB staged records
    __shared__ unsigned short sbuck[STAGE];         // 4 KB slot->bucket
    __shared__ int wcur[MAXBUCK];                   // running global cursor
    __shared__ int shist[MAXBUCK];                  // sub-batch counts
    __shared__ int sbase[MAXBUCK];                  // sub-batch exclusive scan
    __shared__ int scur[MAXBUCK];                   // sub-batch scatter cursor
    __shared__ int wsum[8];                         // wave totals for scan
    int tid = threadIdx.x, blk = blockIdx.x;
    int lane = tid & 63, wav = tid >> 6;
    int lo = blk * chunk, hi = min(E, lo + chunk), cnt = hi - lo;

    if (tid < nbuck) wcur[tid] = hoffpad[tid * nblk + blk];
    __syncthreads();

    int nsb = (cnt + STAGE - 1) / STAGE;
    for (int sb = 0; sb < nsb; ++sb) {
        int s0 = sb * STAGE, s1 = min(cnt, s0 + STAGE), scnt = s1 - s0;
        if (tid < nbuck) shist[tid] = 0;
        __syncthreads();
        for (int i = s0 + tid; i < s1; i += BUILD_T)
            atomicAdd(&shist[esrc[lo + i] >> 8], 1);
        __syncthreads();
        // wave-level exclusive scan over nbuck (<=512) entries
        int v = (tid < nbuck) ? shist[tid] : 0;
        int x = v;
        #pragma unroll
        for (int off = 1; off < 64; off <<= 1) {
            int t = __shfl_up(x, off);
            if (lane >= off) x += t;
        }
        if (lane == 63) wsum[wav] = x;
        __syncthreads();
        if (tid < 8) {
            int w = wsum[tid];
            #pragma unroll
            for (int off = 1; off < 8; off <<= 1) {
                int t = __shfl_up(w, off, 8);
                if (tid >= off) w += t;
            }
            wsum[tid] = w;                          // inclusive wave totals
        }
        __syncthreads();
        int base = (wav > 0) ? wsum[wav - 1] : 0;
        if (tid < nbuck) {
            int ex = x + base - v;
            sbase[tid] = ex;
            scur[tid]  = ex;
        }
        __syncthreads();
        // compute physics from SEQUENTIAL inputs; scatter record into LDS
        for (int i = s0 + tid; i < s1; i += BUILD_T) {
            int gi = lo + i;
            int s = esrc[gi], d = edst[gi];
            int b = s >> 8;
            float r  = dist[gi] * INV_B;
            float vx = vec[3*gi+0] * INV_B;
            float vy = vec[3*gi+1] * INV_B;
            float vz = vec[3*gi+2] * INV_B;
            float ps = pol[s] * INV_B3;
            float pd = pol[d] * INV_B3;
            float r2 = r * r;
            float r3 = r2 * r;
            float u  = r3 * rsqrtf(ps * pd);
            float em = __expf(-DM * u);
            float l3m = 1.0f - em;
            float l5m = 1.0f - (1.0f + DM * u) * em;
            float inv_r3 = 1.0f / r3;
            float inv_r5 = inv_r3 / r2;
            float c1 = l3m * inv_r3;                // > 0 always (nonzero flag)
            float sw = sqrtf(3.0f * l5m * inv_r5);
            float ec = (1.0f - __expf(-DF * u)) * chg[d] * inv_r3;
            float g  = ec / sw;
            uint4 rc;
            rc.x = (unsigned)(d | ((s & 255) << 20));
            rc.y = __float_as_uint(c1);
            rc.z = packh2(sw * vx, sw * vy);
            rc.w = packh2(sw * vz, g);
            int sl = atomicAdd(&scur[b], 1);
            stg[sl]   = rc;
            sbuck[sl] = (unsigned short)b;
        }
        __syncthreads();
        // dump staged records: consecutive threads -> consecutive global slots
        for (int k = tid; k < scnt; k += BUILD_T) {
            int b = sbuck[k];
            recs[wcur[b] + (k - sbase[b])] = stg[k];
        }
        __syncthreads();
        if (tid < nbuck) wcur[tid] += shist[tid];
        __syncthreads();
    }
    // zero-fill pad tails (completes last lines of each run)
    if (tid < nbuck) {
        int base = hoffpad[tid * nblk + blk];
        int end  = base + hpad[tid * nblk + blk];
        for (int s2 = wcur[tid]; s2 < end; ++s2) recs[s2] = make_uint4(0, 0, 0, 0);
    }
}

// ---- per-bucket counting sort -> tight row-CSR 12B records + fused E0/mu0 ----

__global__ void sort_kernel(const int* __restrict__ bktptr, const int* __restrict__ tight,
                            const uint4* __restrict__ recs_raw,
                            unsigned* __restrict__ srt,
                            int* __restrict__ rowptr, const float* __restrict__ pol,
                            float4* __restrict__ E0, float4* __restrict__ mu, int N)
{
    __shared__ int hist[256];
    __shared__ int cur[256];
    __shared__ float acc[256 * 3];
    __shared__ int wsum4[4];
    int tid = threadIdx.x, b = blockIdx.x;          // 512 threads
    int lane = tid & 63, wav = tid >> 6;
    int j0 = bktptr[b], j1 = bktptr[b + 1];
    int tight0 = tight[b];                          // tight start of this bucket
    if (tid < 256) hist[tid] = 0;
    for (int k = tid; k < 768; k += blockDim.x) acc[k] = 0.f;
    __syncthreads();
    for (int j = j0 + tid; j < j1; j += blockDim.x) {
        uint4 rc = recs_raw[j];
        if (rc.y) atomicAdd(&hist[rc.x >> 20], 1);
    }
    __syncthreads();
    // wave-level exclusive scan of 256-entry hist (waves 0..3)
    int v = (tid < 256) ? hist[tid] : 0;
    int x = v;
    #pragma unroll
    for (int off = 1; off < 64; off <<= 1) {
        int t = __shfl_up(x, off);
        if (lane >= off) x += t;
    }
    if (lane == 63 && wav < 4) wsum4[wav] = x;
    __syncthreads();
    if (tid < 4) {
        int w = wsum4[tid];
        #pragma unroll
        for (int off = 1; off < 4; off <<= 1) {
            int t = __shfl_up(w, off, 4);
            if (tid >= off) w += t;
        }
        wsum4[tid] = w;
    }
    __syncthreads();
    if (tid < 256) {
        int base = (wav > 0) ? wsum4[wav - 1] : 0;
        int beg = tight0 + x + base - v;            // exclusive
        cur[tid] = beg;
        int row = b * 256 + tid;
        if (row < N) rowptr[row] = beg;
    }
    __syncthreads();
    for (int j = j0 + tid; j < j1; j += blockDim.x) {
        uint4 rc = recs_raw[j];
        if (rc.y) {
            int lr = (int)(rc.x >> 20);
            int slot = atomicAdd(&cur[lr], 1);
            float c1 = __uint_as_float(rc.y);
            float wx = unph_lo(rc.z), wy = unph_hi(rc.z);
            float wz = unph_lo(rc.w), g  = unph_hi(rc.w);
            srt[3*slot+0] = rc.x;
            srt[3*slot+1] = packh2(c1, wx);
            srt[3*slot+2] = packh2(wy, wz);
            atomicAdd(&acc[lr*3+0], g * wx);        // fused E0 accumulation
            atomicAdd(&acc[lr*3+1], g * wy);
            atomicAdd(&acc[lr*3+2], g * wz);
        }
    }
    __syncthreads();
    if (tid < 256) {
        int row = b * 256 + tid;
        if (row < N) {
            float ax = acc[tid*3], ay = acc[tid*3+1], az = acc[tid*3+2];
            E0[row] = make_float4(ax, ay, az, 0.f);
            float a = pol[row] * INV_B3;
            mu[row] = make_float4(a * ax, a * ay, a * az, 0.f);
        }
    }
}

// ---------------- iterate: row-CSR gather, 16 lanes/row, no atomics ----------------

__global__ void mvg_kernel(const int* __restrict__ rowptr,
                           const unsigned* __restrict__ srt, const float4* __restrict__ E0,
                           const float* __restrict__ pol,
                           const float4* __restrict__ mu_in, float4* __restrict__ mu_out,
                           float* __restrict__ energy, int N, int final_iter)
{
    int tid  = threadIdx.x;
    int lane = tid & 15;
    int row  = (blockIdx.x * blockDim.x + tid) >> 4;
    if (row >= N) return;
    int r0 = rowptr[row], r1 = rowptr[row + 1];
    float ax = 0.f, ay = 0.f, az = 0.f;
    for (int j = r0 + lane; j < r1; j += 16) {
        unsigned pk = srt[3*j+0];
        unsigned w0 = srt[3*j+1];
        unsigned w1 = srt[3*j+2];
        float4 m = mu_in[pk & 0xFFFFF];             // random 16B, L2-resident 1.6MB
        float c1 = unph_lo(w0);
        float wx = unph_hi(w0), wy = unph_lo(w1), wz = unph_hi(w1);
        float dot = wx * m.x + wy * m.y + wz * m.z;
        ax += c1 * m.x - dot * wx;
        ay += c1 * m.y - dot * wy;
        az += c1 * m.z - dot * wz;
    }
    for (int msk = 8; msk >= 1; msk >>= 1) {
        ax += __shfl_xor(ax, msk);
        ay += __shfl_xor(ay, msk);
        az += __shfl_xor(az, msk);
    }
    if (lane == 0) {
        float4 e0 = E0[row];
        float a = pol[row] * INV_B3;
        float mx = a * (e0.x - ax);
        float my = a * (e0.y - ay);
        float mz = a * (e0.z - az);
        mu_out[row] = make_float4(mx, my, mz, 0.f);
        if (final_iter)
            energy[row] = -0.5f * (mx * e0.x + my * e0.y + mz * e0.z);
    }
}

// ---------------- middle path: bucket iterate on padded recs ----------------

__global__ void e0b_kernel(const int* __restrict__ bktptr, const uint4* __restrict__ recs,
                           const float* __restrict__ pol,
                           float4* __restrict__ E0, float4* __restrict__ mu, int N)
{
    __shared__ float acc[256 * 3];
    int tid = threadIdx.x, b = blockIdx.x;
    for (int k = tid; k < 768; k += 256) acc[k] = 0.f;
    __syncthreads();
    int j0 = bktptr[b], j1 = bktptr[b + 1];
    for (int j = j0 + tid; j < j1; j += 256) {
        uint4 rc = recs[j];
        int lr = (int)(rc.x >> 20) & 255;
        float g = unph_hi(rc.w);
        atomicAdd(&acc[lr*3+0], g * unph_lo(rc.z));
        atomicAdd(&acc[lr*3+1], g * unph_hi(rc.z));
        atomicAdd(&acc[lr*3+2], g * unph_lo(rc.w));
    }
    __syncthreads();
    int r = b * 256 + tid;
    if (r < N) {
        float ax = acc[tid*3], ay = acc[tid*3+1], az = acc[tid*3+2];
        E0[r] = make_float4(ax, ay, az, 0.f);
        float a = pol[r] * INV_B3;
        mu[r] = make_float4(a * ax, a * ay, a * az, 0.f);
    }
}

__global__ void mvb_kernel(const int* __restrict__ bktptr, const uint4* __restrict__ recs,
                           const float4* __restrict__ E0, const float* __restrict__ pol,
                           const float4* __restrict__ mu_in, float4* __restrict__ mu_out,
                           float* __restrict__ energy, int N, int final_iter)
{
    __shared__ float acc[256 * 3];
    int tid = threadIdx.x, b = blockIdx.x;
    for (int k = tid; k < 768; k += 256) acc[k] = 0.f;
    __syncthreads();
    int j0 = bktptr[b], j1 = bktptr[b + 1];
    for (int j = j0 + tid; j < j1; j += 256) {
        uint4 rc = recs[j];
        float4 m = mu_in[rc.x & 0xFFFFF];
        float c1 = __uint_as_float(rc.y);
        float wx = unph_lo(rc.z), wy = unph_hi(rc.z), wz = unph_lo(rc.w);
        float dot = wx * m.x + wy * m.y + wz * m.z;
        int lr = (int)(rc.x >> 20) & 255;
        atomicAdd(&acc[lr*3+0], c1 * m.x - dot * wx);
        atomicAdd(&acc[lr*3+1], c1 * m.y - dot * wy);
        atomicAdd(&acc[lr*3+2], c1 * m.z - dot * wz);
    }
    __syncthreads();
    int r = b * 256 + tid;
    if (r < N) {
        float4 e0 = E0[r];
        float a = pol[r] * INV_B3;
        float mx = a * (e0.x - acc[tid*3+0]);
        float my = a * (e0.y - acc[tid*3+1]);
        float mz = a * (e0.z - acc[tid*3+2]);
        mu_out[r] = make_float4(mx, my, mz, 0.f);
        if (final_iter)
            energy[r] = -0.5f * (mx * e0.x + my * e0.y + mz * e0.z);
    }
}

// ---------------- fallback (atomic path, tiny ws) ----------------

__global__ void fb_e0_kernel(const int* esrc, const int* edst, const float* dist,
                             const float* vec, const float* pol, const float* chg,
                             float4* E0, int E)
{
    int e = blockIdx.x * blockDim.x + threadIdx.x;
    if (e >= E) return;
    int s = esrc[e], d = edst[e];
    float r  = dist[e] * INV_B;
    float vx = vec[3*e+0]*INV_B, vy = vec[3*e+1]*INV_B, vz = vec[3*e+2]*INV_B;
    float r3 = r*r*r;
    float u  = r3 * rsqrtf(pol[s]*INV_B3 * pol[d]*INV_B3);
    float ec = (1.0f - __expf(-DF*u)) * chg[d] / r3;
    atomicAdd(&E0[s].x, ec*vx); atomicAdd(&E0[s].y, ec*vy); atomicAdd(&E0[s].z, ec*vz);
}

__global__ void fb_init_kernel(const float* pol, const float4* E0, float4* mu, float4* acc, int N)
{
    int i = blockIdx.x * blockDim.x + threadIdx.x;
    if (i >= N) return;
    float a = pol[i]*INV_B3; float4 e0 = E0[i];
    mu[i]  = make_float4(a*e0.x, a*e0.y, a*e0.z, 0.f);
    acc[i] = make_float4(0.f,0.f,0.f,0.f);
}

__global__ void fb_matvec_kernel(const int* esrc, const int* edst, const float* dist,
                                 const float* vec, const float* pol,
                                 const float4* mu, float4* acc, int E)
{
    int e = blockIdx.x * blockDim.x + threadIdx.x;
    if (e >= E) return;
    int s = esrc[e], d = edst[e];
    float r  = dist[e]*INV_B;
    float vx = vec[3*e+0]*INV_B, vy = vec[3*e+1]*INV_B, vz = vec[3*e+2]*INV_B;
    float r2 = r*r, r3 = r2*r;
    float u  = r3 * rsqrtf(pol[s]*INV_B3 * pol[d]*INV_B3);
    float em = __expf(-DM*u);
    float c1 = (1.0f - em) / r3;
    float c2 = 3.0f * (1.0f - (1.0f + DM*u)*em) / (r3*r2);
    float4 m = mu[d];
    float k = c2 * (vx*m.x + vy*m.y + vz*m.z);
    atomicAdd(&acc[s].x, c1*m.x - k*vx);
    atomicAdd(&acc[s].y, c1*m.y - k*vy);
    atomicAdd(&acc[s].z, c1*m.z - k*vz);
}

__global__ void fb_update_kernel(const float* pol, const float4* E0, float4* acc,
                                 float4* mu, float* energy, int N, int final_iter)
{
    int i = blockIdx.x * blockDim.x + threadIdx.x;
    if (i >= N) return;
    float a = pol[i]*INV_B3; float4 e0 = E0[i]; float4 ac = acc[i];
    float mx = a*(e0.x-ac.x), my = a*(e0.y-ac.y), mz = a*(e0.z-ac.z);
    mu[i]  = make_float4(mx,my,mz,0.f);
    acc[i] = make_float4(0.f,0.f,0.f,0.f);
    if (final_iter) energy[i] = -0.5f*(mx*e0.x + my*e0.y + mz*e0.z);
}

// ---------------- launch ----------------

static inline size_t align_up(size_t x, size_t a) { return (x + a - 1) & ~(a - 1); }

struct Layout {
    int chunk, nblk, nScan, g1;
    size_t o_hpad, o_hoffpad, o_bsum1, o_bkt, o_braw, o_tight;
    size_t o_E0, o_mua, o_mub, o_recsraw;
    size_t need_mid;
    size_t o_rowptr, o_srt;
    size_t need_sort;
};

static Layout make_layout(int E, int N, int nbuck, int chunk)
{
    Layout L;
    L.chunk = chunk;
    L.nblk  = (E + chunk - 1) / chunk;
    L.nScan = nbuck * L.nblk;
    L.g1    = (L.nScan + SCAN_B - 1) / SCAN_B;
    size_t Epad = (size_t)E + 7u * (size_t)L.nScan;   // worst-case padding
    size_t off = 0;
    auto carve = [&](size_t bytes) { size_t o = off; off = align_up(off + bytes, 256); return o; };
    L.o_hpad    = carve((size_t)L.nScan * 4);
    L.o_hoffpad = carve((size_t)L.nScan * 4);
    L.o_bsum1   = carve(1024 * 4);
    L.o_bkt     = carve((size_t)(nbuck + 1) * 4);
    L.o_braw    = carve((size_t)nbuck * 4);
    L.o_tight   = carve((size_t)nbuck * 4);
    L.o_E0      = carve((size_t)N * 16);
    L.o_mua     = carve((size_t)N * 16);
    L.o_mub     = carve((size_t)N * 16);
    L.o_recsraw = carve(Epad * 16);
    L.need_mid  = off;
    L.o_rowptr  = carve((size_t)(N + 1) * 4);
    L.o_srt     = carve((size_t)E * 12);
    L.need_sort = off;
    return L;
}

extern "C" void kernel_launch(void* const* d_in, const int* in_sizes, int n_in,
                              void* d_out, int out_size, void* d_ws, size_t ws_size,
                              hipStream_t stream)
{
    // inputs: species, edge_src, edge_dst, distances, vec, polarisability, charges
    const int*   esrc = (const int*)  d_in[1];
    const int*   edst = (const int*)  d_in[2];
    const float* dist = (const float*)d_in[3];
    const float* vec  = (const float*)d_in[4];
    const float* pol  = (const float*)d_in[5];
    const float* chg  = (const float*)d_in[6];
    const int E = in_sizes[1];
    const int N = in_sizes[5];
    float* out = (float*)d_out;

    const int nbuck = (N + 255) >> 8;                  // 391 for N=100k

    // pick smallest chunk whose worst-case carve fits (more blocks = better balance)
    const int cand[4] = {4096, 8192, 16384, 32768};
    Layout L{}; bool ok_sort = false, ok_mid = false;
    for (int ci = 0; ci < 4; ++ci) {
        Layout t = make_layout(E, N, nbuck, cand[ci]);
        bool shp = (nbuck <= MAXBUCK) && (t.g1 <= 1024) && (nbuck >= 1) && (N < (1 << 20));
        if (shp && ws_size >= t.need_sort) { L = t; ok_sort = true; break; }
    }
    if (!ok_sort) {
        Layout t = make_layout(E, N, nbuck, 32768);
        bool shp = (nbuck <= MAXBUCK) && (t.g1 <= 1024) && (nbuck >= 1) && (N < (1 << 20));
        if (shp && ws_size >= t.need_mid) { L = t; ok_mid = true; }
    }

    char* ws = (char*)d_ws;

    if (ok_sort || ok_mid) {
        int*    hpad    = (int*)   (ws + L.o_hpad);
        int*    hoffpad = (int*)   (ws + L.o_hoffpad);
        int*    bsum1   = (int*)   (ws + L.o_bsum1);
        int*    bktptr  = (int*)   (ws + L.o_bkt);
        int*    braw    = (int*)   (ws + L.o_braw);
        int*    tight   = (int*)   (ws + L.o_tight);
        float4* E0      = (float4*)(ws + L.o_E0);
        float4* mu_a    = (float4*)(ws + L.o_mua);
        float4* mu_b    = (float4*)(ws + L.o_mub);
        uint4*  recsraw = (uint4*) (ws + L.o_recsraw);
        int*    rowptr  = ok_sort ? (int*)(ws + L.o_rowptr) : nullptr;

        hipMemsetAsync(braw, 0, (size_t)nbuck * 4, stream);
        bhist_kernel<<<L.nblk, BUILD_T, 0, stream>>>(esrc, braw, hpad, E, nbuck,
                                                     L.nblk, L.chunk);
        scan1_kernel<<<L.g1, SCAN_B, 0, stream>>>(hpad, hoffpad, bsum1, L.nScan);
        scan2_kernel<<<1, 1024, 0, stream>>>(bsum1, L.g1);
        scan3_kernel<<<L.g1, SCAN_B, 0, stream>>>(hoffpad, bsum1, L.nScan);
        bktptr_kernel<<<1, BUILD_T, 0, stream>>>(hoffpad, hpad, braw, bktptr, tight,
                                                 rowptr, nbuck, L.nblk, L.nScan, N, E);
        build_kernel<<<L.nblk, BUILD_T, 0, stream>>>(esrc, edst, dist, vec, pol, chg,
                                                     hoffpad, hpad, recsraw,
                                                     E, nbuck, L.nblk, L.chunk);

        if (ok_sort) {
            unsigned* srt = (unsigned*)(ws + L.o_srt);

            sort_kernel<<<nbuck, 512, 0, stream>>>(bktptr, tight, recsraw,
                                                   srt, rowptr, pol, E0, mu_a, N);

            const int NG16 = (N + 15) / 16;
            float4* min_ = mu_a; float4* mout_ = mu_b;
            for (int it = 0; it < NITER; ++it) {
                mvg_kernel<<<NG16, 256, 0, stream>>>(rowptr, srt, E0, pol,
                                                     min_, mout_, out, N, it == NITER - 1);
                float4* t = min_; min_ = mout_; mout_ = t;
            }
        } else {
            e0b_kernel<<<nbuck, 256, 0, stream>>>(bktptr, recsraw, pol, E0, mu_a, N);
            float4* min_ = mu_a; float4* mout_ = mu_b;
            for (int it = 0; it < NITER; ++it) {
                mvb_kernel<<<nbuck, 256, 0, stream>>>(bktptr, recsraw, E0, pol,
                                                      min_, mout_, out, N, it == NITER - 1);
                float4* t = min_; min_ = mout_; mout_ = t;
            }
        }
    } else {
        // fallback: atomic scatter path (needs 48B/node)
        float4* E0  = (float4*)(ws);
        float4* mu  = (float4*)(ws + (size_t)N * 16);
        float4* acc = (float4*)(ws + (size_t)N * 32);
        const int EB = 256, NB = 256;
        const int EG = (E + EB - 1) / EB;
        const int NG = (N + NB - 1) / NB;
        hipMemsetAsync(E0, 0, (size_t)N * 16, stream);
        fb_e0_kernel<<<EG, EB, 0, stream>>>(esrc, edst, dist, vec, pol, chg, E0, E);
        fb_init_kernel<<<NG, NB, 0, stream>>>(pol, E0, mu, acc, N);
        for (int it = 0; it < NITER; ++it) {
            fb_matvec_kernel<<<EG, EB, 0, stream>>>(esrc, edst, dist, vec, pol, mu, acc, E);
            fb_update_kernel<<<NG, NB, 0, stream>>>(pol, E0, acc, mu, out, N, it == NITER - 1);
        }
    }
}

// Round 12
// 324.289 us; speedup vs baseline: 1.1033x; 1.1033x over previous
//
#include <hip/hip_runtime.h>
#include <hip/hip_fp16.h>

// Polarisation solver v12: tight (pad-free) bucket build with 4096-record LDS
// staging (long coalesced runs); per-bucket counting sort -> row-CSR 12B
// records + fused E0/mu0; atomic-free row-gather Jacobi iterations.
// raw record (16B) = {dst|(localrow<<20), c1 f32, wx|wy f16x2, wz|g f16x2}.
// sorted record (12B) = {dst|(lr<<20), c1|wx f16x2, wy|wz f16x2}.

static constexpr float INV_B  = 1.0f / 0.52917721067f;            // 1/BOHR
static constexpr float INV_B3 = INV_B * INV_B * INV_B;            // 1/BOHR^3
static constexpr float DM = 0.39f;                                 // DAMP_MUTUAL
static constexpr float DF = 0.7f;                                  // DAMP_FIELD
static constexpr int   NITER = 7;
#define SCAN_B 1024
#define STAGE 4096
#define BUILD_T 512
#define MAXBUCK 512

__device__ inline unsigned packh2(float a, float b) {
    return (unsigned)__half_as_ushort(__float2half_rn(a)) |
           ((unsigned)__half_as_ushort(__float2half_rn(b)) << 16);
}
__device__ inline float unph_lo(unsigned u) {
    return __half2float(__ushort_as_half((unsigned short)(u & 0xFFFFu)));
}
__device__ inline float unph_hi(unsigned u) {
    return __half2float(__ushort_as_half((unsigned short)(u >> 16)));
}

// ---- build: per-(block,bucket) histogram (tight counts, bucket-major) ----

__global__ void bhist_kernel(const int* __restrict__ esrc, int* __restrict__ h,
                             int E, int nbuck, int nblk, int chunk)
{
    __shared__ int cnt[MAXBUCK];
    int tid = threadIdx.x, blk = blockIdx.x;
    for (int b = tid; b < nbuck; b += blockDim.x) cnt[b] = 0;
    __syncthreads();
    int lo = blk * chunk, hi = min(E, lo + chunk);
    for (int i = lo + tid; i < hi; i += blockDim.x)
        atomicAdd(&cnt[esrc[i] >> 8], 1);
    __syncthreads();
    for (int b = tid; b < nbuck; b += blockDim.x)
        h[b * nblk + blk] = cnt[b];
}

// ---------------- 2-level exclusive scan (width 1024) ----------------

__global__ void scan1_kernel(const int* __restrict__ in, int* __restrict__ excl,
                             int* __restrict__ blocksum, int n)
{
    __shared__ int sh[SCAN_B];
    int tid = threadIdx.x;
    int i = blockIdx.x * SCAN_B + tid;
    int v = (i < n) ? in[i] : 0;
    sh[tid] = v;
    __syncthreads();
    for (int off = 1; off < SCAN_B; off <<= 1) {
        int t = (tid >= off) ? sh[tid - off] : 0;
        __syncthreads();
        sh[tid] += t;
        __syncthreads();
    }
    if (i < n) excl[i] = sh[tid] - v;
    if (tid == SCAN_B - 1) blocksum[blockIdx.x] = sh[tid];
}

__global__ void scan2_kernel(int* __restrict__ blocksum, int nb)
{
    __shared__ int sh[1024];
    int tid = threadIdx.x;
    int v = (tid < nb) ? blocksum[tid] : 0;
    sh[tid] = v;
    __syncthreads();
    for (int off = 1; off < 1024; off <<= 1) {
        int t = (tid >= off) ? sh[tid - off] : 0;
        __syncthreads();
        sh[tid] += t;
        __syncthreads();
    }
    if (tid < nb) blocksum[tid] = sh[tid] - v;
}

__global__ void scan3_kernel(int* __restrict__ excl, const int* __restrict__ blocksum, int n)
{
    int i = blockIdx.x * SCAN_B + threadIdx.x;
    if (i < n) excl[i] += blocksum[blockIdx.x];
}

// ---- bucket pointers (tight starts) ----

__global__ void bktptr_kernel(const int* __restrict__ hoff,
                              int* __restrict__ bktptr, int* __restrict__ rowptr,
                              int nbuck, int nblk, int N, int E)
{
    int b = blockIdx.x * blockDim.x + threadIdx.x;
    if (b < nbuck) bktptr[b] = hoff[b * nblk];
    if (b == nbuck) {
        bktptr[b] = E;
        if (rowptr) rowptr[N] = E;
    }
}

// ---- build: sequential reads, LDS bucket-sorted staging, coalesced dump ----
// matvec term: t = c1*mu_d - (w.mu_d)*w, w = sqrt(3*l5m*inv_r5)*vec_ij.
// E0 term: g*w with g = l3f*q_d*inv_r3 / sw.

__global__ __launch_bounds__(BUILD_T)
void build_kernel(const int* __restrict__ esrc, const int* __restrict__ edst,
                  const float* __restrict__ dist, const float* __restrict__ vec,
                  const float* __restrict__ pol, const float* __restrict__ chg,
                  const int* __restrict__ hoff,
                  uint4* __restrict__ recs, int E, int nbuck, int nblk, int chunk)
{
    __shared__ uint4 stg[STAGE];                    // 64 KB staged records
    __shared__ unsigned short sbuck[STAGE];         // 8 KB slot->bucket
    __shared__ int wcur[MAXBUCK];                   // running global cursor
    __shared__ int shist[MAXBUCK];                  // sub-batch counts
    __shared__ int sbase[MAXBUCK];                  // sub-batch exclusive scan
    __shared__ int scur[MAXBUCK];                   // sub-batch scatter cursor
    __shared__ int wsum[8];                         // wave totals for scan
    int tid = threadIdx.x, blk = blockIdx.x;
    int lane = tid & 63, wav = tid >> 6;
    int lo = blk * chunk, hi = min(E, lo + chunk), cnt = hi - lo;

    if (tid < nbuck) wcur[tid] = hoff[tid * nblk + blk];
    __syncthreads();

    int nsb = (cnt + STAGE - 1) / STAGE;
    for (int sb = 0; sb < nsb; ++sb) {
        int s0 = sb * STAGE, s1 = min(cnt, s0 + STAGE), scnt = s1 - s0;
        if (tid < nbuck) shist[tid] = 0;
        __syncthreads();
        for (int i = s0 + tid; i < s1; i += BUILD_T)
            atomicAdd(&shist[esrc[lo + i] >> 8], 1);
        __syncthreads();
        // wave-level exclusive scan over nbuck (<=512) entries
        int v = (tid < nbuck) ? shist[tid] : 0;
        int x = v;
        #pragma unroll
        for (int off = 1; off < 64; off <<= 1) {
            int t = __shfl_up(x, off);
            if (lane >= off) x += t;
        }
        if (lane == 63) wsum[wav] = x;
        __syncthreads();
        if (tid < 8) {
            int w = wsum[tid];
            #pragma unroll
            for (int off = 1; off < 8; off <<= 1) {
                int t = __shfl_up(w, off, 8);
                if (tid >= off) w += t;
            }
            wsum[tid] = w;                          // inclusive wave totals
        }
        __syncthreads();
        int base = (wav > 0) ? wsum[wav - 1] : 0;
        if (tid < nbuck) {
            int ex = x + base - v;
            sbase[tid] = ex;
            scur[tid]  = ex;
        }
        __syncthreads();
        // compute physics from SEQUENTIAL inputs; scatter record into LDS
        for (int i = s0 + tid; i < s1; i += BUILD_T) {
            int gi = lo + i;
            int s = esrc[gi], d = edst[gi];
            int b = s >> 8;
            float r  = dist[gi] * INV_B;
            float vx = vec[3*gi+0] * INV_B;
            float vy = vec[3*gi+1] * INV_B;
            float vz = vec[3*gi+2] * INV_B;
            float ps = pol[s] * INV_B3;
            float pd = pol[d] * INV_B3;
            float r2 = r * r;
            float r3 = r2 * r;
            float u  = r3 * rsqrtf(ps * pd);
            float em = __expf(-DM * u);
            float l3m = 1.0f - em;
            float l5m = 1.0f - (1.0f + DM * u) * em;
            float inv_r3 = 1.0f / r3;
            float inv_r5 = inv_r3 / r2;
            float c1 = l3m * inv_r3;
            float sw = sqrtf(3.0f * l5m * inv_r5);
            float ec = (1.0f - __expf(-DF * u)) * chg[d] * inv_r3;
            float g  = ec / sw;
            uint4 rc;
            rc.x = (unsigned)(d | ((s & 255) << 20));
            rc.y = __float_as_uint(c1);
            rc.z = packh2(sw * vx, sw * vy);
            rc.w = packh2(sw * vz, g);
            int sl = atomicAdd(&scur[b], 1);
            stg[sl]   = rc;
            sbuck[sl] = (unsigned short)b;
        }
        __syncthreads();
        // dump staged records: consecutive threads -> consecutive global slots
        for (int k = tid; k < scnt; k += BUILD_T) {
            int b = sbuck[k];
            recs[wcur[b] + (k - sbase[b])] = stg[k];
        }
        __syncthreads();
        if (tid < nbuck) wcur[tid] += shist[tid];
        __syncthreads();
    }
}

// ---- per-bucket counting sort -> tight row-CSR 12B records + fused E0/mu0 ----

__global__ void sort_kernel(const int* __restrict__ bktptr,
                            const uint4* __restrict__ recs_raw,
                            unsigned* __restrict__ srt,
                            int* __restrict__ rowptr, const float* __restrict__ pol,
                            float4* __restrict__ E0, float4* __restrict__ mu, int N)
{
    __shared__ int hist[256];
    __shared__ int cur[256];
    __shared__ float acc[256 * 3];
    __shared__ int wsum4[4];
    int tid = threadIdx.x, b = blockIdx.x;          // 512 threads
    int lane = tid & 63, wav = tid >> 6;
    int j0 = bktptr[b], j1 = bktptr[b + 1];
    if (tid < 256) hist[tid] = 0;
    for (int k = tid; k < 768; k += blockDim.x) acc[k] = 0.f;
    __syncthreads();
    for (int j = j0 + tid; j < j1; j += blockDim.x)
        atomicAdd(&hist[recs_raw[j].x >> 20], 1);
    __syncthreads();
    // wave-level exclusive scan of 256-entry hist (waves 0..3)
    int v = (tid < 256) ? hist[tid] : 0;
    int x = v;
    #pragma unroll
    for (int off = 1; off < 64; off <<= 1) {
        int t = __shfl_up(x, off);
        if (lane >= off) x += t;
    }
    if (lane == 63 && wav < 4) wsum4[wav] = x;
    __syncthreads();
    if (tid < 4) {
        int w = wsum4[tid];
        #pragma unroll
        for (int off = 1; off < 4; off <<= 1) {
            int t = __shfl_up(w, off, 4);
            if (tid >= off) w += t;
        }
        wsum4[tid] = w;
    }
    __syncthreads();
    if (tid < 256) {
        int base = (wav > 0) ? wsum4[wav - 1] : 0;
        int beg = j0 + x + base - v;                // tight: bucket base == j0
        cur[tid] = beg;
        int row = b * 256 + tid;
        if (row < N) rowptr[row] = beg;
    }
    __syncthreads();
    for (int j = j0 + tid; j < j1; j += blockDim.x) {
        uint4 rc = recs_raw[j];
        int lr = (int)(rc.x >> 20);
        int slot = atomicAdd(&cur[lr], 1);
        float c1 = __uint_as_float(rc.y);
        float wx = unph_lo(rc.z), wy = unph_hi(rc.z);
        float wz = unph_lo(rc.w), g  = unph_hi(rc.w);
        srt[3*slot+0] = rc.x;
        srt[3*slot+1] = packh2(c1, wx);
        srt[3*slot+2] = packh2(wy, wz);
        atomicAdd(&acc[lr*3+0], g * wx);            // fused E0 accumulation
        atomicAdd(&acc[lr*3+1], g * wy);
        atomicAdd(&acc[lr*3+2], g * wz);
    }
    __syncthreads();
    if (tid < 256) {
        int row = b * 256 + tid;
        if (row < N) {
            float ax = acc[tid*3], ay = acc[tid*3+1], az = acc[tid*3+2];
            E0[row] = make_float4(ax, ay, az, 0.f);
            float a = pol[row] * INV_B3;
            mu[row] = make_float4(a * ax, a * ay, a * az, 0.f);
        }
    }
}

// ---------------- iterate: row-CSR gather, 16 lanes/row, no atomics ----------------

__global__ void mvg_kernel(const int* __restrict__ rowptr,
                           const unsigned* __restrict__ srt, const float4* __restrict__ E0,
                           const float* __restrict__ pol,
                           const float4* __restrict__ mu_in, float4* __restrict__ mu_out,
                           float* __restrict__ energy, int N, int final_iter)
{
    int tid  = threadIdx.x;
    int lane = tid & 15;
    int row  = (blockIdx.x * blockDim.x + tid) >> 4;
    if (row >= N) return;
    int r0 = rowptr[row], r1 = rowptr[row + 1];
    float ax = 0.f, ay = 0.f, az = 0.f;
    for (int j = r0 + lane; j < r1; j += 16) {
        unsigned pk = srt[3*j+0];
        unsigned w0 = srt[3*j+1];
        unsigned w1 = srt[3*j+2];
        float4 m = mu_in[pk & 0xFFFFF];             // random 16B, L2-resident 1.6MB
        float c1 = unph_lo(w0);
        float wx = unph_hi(w0), wy = unph_lo(w1), wz = unph_hi(w1);
        float dot = wx * m.x + wy * m.y + wz * m.z;
        ax += c1 * m.x - dot * wx;
        ay += c1 * m.y - dot * wy;
        az += c1 * m.z - dot * wz;
    }
    for (int msk = 8; msk >= 1; msk >>= 1) {
        ax += __shfl_xor(ax, msk);
        ay += __shfl_xor(ay, msk);
        az += __shfl_xor(az, msk);
    }
    if (lane == 0) {
        float4 e0 = E0[row];
        float a = pol[row] * INV_B3;
        float mx = a * (e0.x - ax);
        float my = a * (e0.y - ay);
        float mz = a * (e0.z - az);
        mu_out[row] = make_float4(mx, my, mz, 0.f);
        if (final_iter)
            energy[row] = -0.5f * (mx * e0.x + my * e0.y + mz * e0.z);
    }
}

// ---------------- middle path: bucket iterate on tight recs ----------------

__global__ void e0b_kernel(const int* __restrict__ bktptr, const uint4* __restrict__ recs,
                           const float* __restrict__ pol,
                           float4* __restrict__ E0, float4* __restrict__ mu, int N)
{
    __shared__ float acc[256 * 3];
    int tid = threadIdx.x, b = blockIdx.x;
    for (int k = tid; k < 768; k += 256) acc[k] = 0.f;
    __syncthreads();
    int j0 = bktptr[b], j1 = bktptr[b + 1];
    for (int j = j0 + tid; j < j1; j += 256) {
        uint4 rc = recs[j];
        int lr = (int)(rc.x >> 20) & 255;
        float g = unph_hi(rc.w);
        atomicAdd(&acc[lr*3+0], g * unph_lo(rc.z));
        atomicAdd(&acc[lr*3+1], g * unph_hi(rc.z));
        atomicAdd(&acc[lr*3+2], g * unph_lo(rc.w));
    }
    __syncthreads();
    int r = b * 256 + tid;
    if (r < N) {
        float ax = acc[tid*3], ay = acc[tid*3+1], az = acc[tid*3+2];
        E0[r] = make_float4(ax, ay, az, 0.f);
        float a = pol[r] * INV_B3;
        mu[r] = make_float4(a * ax, a * ay, a * az, 0.f);
    }
}

__global__ void mvb_kernel(const int* __restrict__ bktptr, const uint4* __restrict__ recs,
                           const float4* __restrict__ E0, const float* __restrict__ pol,
                           const float4* __restrict__ mu_in, float4* __restrict__ mu_out,
                           float* __restrict__ energy, int N, int final_iter)
{
    __shared__ float acc[256 * 3];
    int tid = threadIdx.x, b = blockIdx.x;
    for (int k = tid; k < 768; k += 256) acc[k] = 0.f;
    __syncthreads();
    int j0 = bktptr[b], j1 = bktptr[b + 1];
    for (int j = j0 + tid; j < j1; j += 256) {
        uint4 rc = recs[j];
        float4 m = mu_in[rc.x & 0xFFFFF];
        float c1 = __uint_as_float(rc.y);
        float wx = unph_lo(rc.z), wy = unph_hi(rc.z), wz = unph_lo(rc.w);
        float dot = wx * m.x + wy * m.y + wz * m.z;
        int lr = (int)(rc.x >> 20) & 255;
        atomicAdd(&acc[lr*3+0], c1 * m.x - dot * wx);
        atomicAdd(&acc[lr*3+1], c1 * m.y - dot * wy);
        atomicAdd(&acc[lr*3+2], c1 * m.z - dot * wz);
    }
    __syncthreads();
    int r = b * 256 + tid;
    if (r < N) {
        float4 e0 = E0[r];
        float a = pol[r] * INV_B3;
        float mx = a * (e0.x - acc[tid*3+0]);
        float my = a * (e0.y - acc[tid*3+1]);
        float mz = a * (e0.z - acc[tid*3+2]);
        mu_out[r] = make_float4(mx, my, mz, 0.f);
        if (final_iter)
            energy[r] = -0.5f * (mx * e0.x + my * e0.y + mz * e0.z);
    }
}

// ---------------- fallback (atomic path, tiny ws) ----------------

__global__ void fb_e0_kernel(const int* esrc, const int* edst, const float* dist,
                             const float* vec, const float* pol, const float* chg,
                             float4* E0, int E)
{
    int e = blockIdx.x * blockDim.x + threadIdx.x;
    if (e >= E) return;
    int s = esrc[e], d = edst[e];
    float r  = dist[e] * INV_B;
    float vx = vec[3*e+0]*INV_B, vy = vec[3*e+1]*INV_B, vz = vec[3*e+2]*INV_B;
    float r3 = r*r*r;
    float u  = r3 * rsqrtf(pol[s]*INV_B3 * pol[d]*INV_B3);
    float ec = (1.0f - __expf(-DF*u)) * chg[d] / r3;
    atomicAdd(&E0[s].x, ec*vx); atomicAdd(&E0[s].y, ec*vy); atomicAdd(&E0[s].z, ec*vz);
}

__global__ void fb_init_kernel(const float* pol, const float4* E0, float4* mu, float4* acc, int N)
{
    int i = blockIdx.x * blockDim.x + threadIdx.x;
    if (i >= N) return;
    float a = pol[i]*INV_B3; float4 e0 = E0[i];
    mu[i]  = make_float4(a*e0.x, a*e0.y, a*e0.z, 0.f);
    acc[i] = make_float4(0.f,0.f,0.f,0.f);
}

__global__ void fb_matvec_kernel(const int* esrc, const int* edst, const float* dist,
                                 const float* vec, const float* pol,
                                 const float4* mu, float4* acc, int E)
{
    int e = blockIdx.x * blockDim.x + threadIdx.x;
    if (e >= E) return;
    int s = esrc[e], d = edst[e];
    float r  = dist[e]*INV_B;
    float vx = vec[3*e+0]*INV_B, vy = vec[3*e+1]*INV_B, vz = vec[3*e+2]*INV_B;
    float r2 = r*r, r3 = r2*r;
    float u  = r3 * rsqrtf(pol[s]*INV_B3 * pol[d]*INV_B3);
    float em = __expf(-DM*u);
    float c1 = (1.0f - em) / r3;
    float c2 = 3.0f * (1.0f - (1.0f + DM*u)*em) / (r3*r2);
    float4 m = mu[d];
    float k = c2 * (vx*m.x + vy*m.y + vz*m.z);
    atomicAdd(&acc[s].x, c1*m.x - k*vx);
    atomicAdd(&acc[s].y, c1*m.y - k*vy);
    atomicAdd(&acc[s].z, c1*m.z - k*vz);
}

__global__ void fb_update_kernel(const float* pol, const float4* E0, float4* acc,
                                 float4* mu, float* energy, int N, int final_iter)
{
    int i = blockIdx.x * blockDim.x + threadIdx.x;
    if (i >= N) return;
    float a = pol[i]*INV_B3; float4 e0 = E0[i]; float4 ac = acc[i];
    float mx = a*(e0.x-ac.x), my = a*(e0.y-ac.y), mz = a*(e0.z-ac.z);
    mu[i]  = make_float4(mx,my,mz,0.f);
    acc[i] = make_float4(0.f,0.f,0.f,0.f);
    if (final_iter) energy[i] = -0.5f*(mx*e0.x + my*e0.y + mz*e0.z);
}

// ---------------- launch ----------------

static inline size_t align_up(size_t x, size_t a) { return (x + a - 1) & ~(a - 1); }

struct Layout {
    int chunk, nblk, nScan, g1;
    size_t o_h, o_hoff, o_bsum, o_bkt, o_E0, o_mua, o_mub, o_recs;
    size_t need_mid;
    size_t o_rowptr, o_srt;
    size_t need_sort;
};

static Layout make_layout(int E, int N, int nbuck, int chunk)
{
    Layout L;
    L.chunk = chunk;
    L.nblk  = (E + chunk - 1) / chunk;
    L.nScan = nbuck * L.nblk;
    L.g1    = (L.nScan + SCAN_B - 1) / SCAN_B;
    size_t off = 0;
    auto carve = [&](size_t bytes) { size_t o = off; off = align_up(off + bytes, 256); return o; };
    L.o_h      = carve((size_t)L.nScan * 4);
    L.o_hoff   = carve((size_t)L.nScan * 4);
    L.o_bsum   = carve(1024 * 4);
    L.o_bkt    = carve((size_t)(nbuck + 1) * 4);
    L.o_E0     = carve((size_t)N * 16);
    L.o_mua    = carve((size_t)N * 16);
    L.o_mub    = carve((size_t)N * 16);
    L.o_recs   = carve((size_t)E * 16);              // tight, no padding
    L.need_mid = off;
    L.o_rowptr = carve((size_t)(N + 1) * 4);
    L.o_srt    = carve((size_t)E * 12);
    L.need_sort = off;
    return L;
}

extern "C" void kernel_launch(void* const* d_in, const int* in_sizes, int n_in,
                              void* d_out, int out_size, void* d_ws, size_t ws_size,
                              hipStream_t stream)
{
    // inputs: species, edge_src, edge_dst, distances, vec, polarisability, charges
    const int*   esrc = (const int*)  d_in[1];
    const int*   edst = (const int*)  d_in[2];
    const float* dist = (const float*)d_in[3];
    const float* vec  = (const float*)d_in[4];
    const float* pol  = (const float*)d_in[5];
    const float* chg  = (const float*)d_in[6];
    const int E = in_sizes[1];
    const int N = in_sizes[5];
    float* out = (float*)d_out;

    const int nbuck = (N + 255) >> 8;                  // 391 for N=100k

    const int cand[3] = {8192, 16384, 32768};
    Layout L{}; bool ok_sort = false, ok_mid = false;
    for (int ci = 0; ci < 3; ++ci) {
        Layout t = make_layout(E, N, nbuck, cand[ci]);
        bool shp = (nbuck <= MAXBUCK) && (t.g1 <= 1024) && (nbuck >= 1) && (N < (1 << 20));
        if (shp && ws_size >= t.need_sort) { L = t; ok_sort = true; break; }
    }
    if (!ok_sort) {
        Layout t = make_layout(E, N, nbuck, 32768);
        bool shp = (nbuck <= MAXBUCK) && (t.g1 <= 1024) && (nbuck >= 1) && (N < (1 << 20));
        if (shp && ws_size >= t.need_mid) { L = t; ok_mid = true; }
    }

    char* ws = (char*)d_ws;

    if (ok_sort || ok_mid) {
        int*    h      = (int*)   (ws + L.o_h);
        int*    hoff   = (int*)   (ws + L.o_hoff);
        int*    bsum   = (int*)   (ws + L.o_bsum);
        int*    bktptr = (int*)   (ws + L.o_bkt);
        float4* E0     = (float4*)(ws + L.o_E0);
        float4* mu_a   = (float4*)(ws + L.o_mua);
        float4* mu_b   = (float4*)(ws + L.o_mub);
        uint4*  recs   = (uint4*) (ws + L.o_recs);
        int*    rowptr = ok_sort ? (int*)(ws + L.o_rowptr) : nullptr;

        bhist_kernel<<<L.nblk, BUILD_T, 0, stream>>>(esrc, h, E, nbuck, L.nblk, L.chunk);
        scan1_kernel<<<L.g1, SCAN_B, 0, stream>>>(h, hoff, bsum, L.nScan);
        scan2_kernel<<<1, 1024, 0, stream>>>(bsum, L.g1);
        scan3_kernel<<<L.g1, SCAN_B, 0, stream>>>(hoff, bsum, L.nScan);
        bktptr_kernel<<<(nbuck + 256) / 256, 256, 0, stream>>>(hoff, bktptr, rowptr,
                                                               nbuck, L.nblk, N, E);
        build_kernel<<<L.nblk, BUILD_T, 0, stream>>>(esrc, edst, dist, vec, pol, chg,
                                                     hoff, recs, E, nbuck, L.nblk, L.chunk);

        if (ok_sort) {
            unsigned* srt = (unsigned*)(ws + L.o_srt);

            sort_kernel<<<nbuck, 512, 0, stream>>>(bktptr, recs, srt, rowptr,
                                                   pol, E0, mu_a, N);

            const int NG16 = (N + 15) / 16;
            float4* min_ = mu_a; float4* mout_ = mu_b;
            for (int it = 0; it < NITER; ++it) {
                mvg_kernel<<<NG16, 256, 0, stream>>>(rowptr, srt, E0, pol,
                                                     min_, mout_, out, N, it == NITER - 1);
                float4* t = min_; min_ = mout_; mout_ = t;
            }
        } else {
            e0b_kernel<<<nbuck, 256, 0, stream>>>(bktptr, recs, pol, E0, mu_a, N);
            float4* min_ = mu_a; float4* mout_ = mu_b;
            for (int it = 0; it < NITER; ++it) {
                mvb_kernel<<<nbuck, 256, 0, stream>>>(bktptr, recs, E0, pol,
                                                      min_, mout_, out, N, it == NITER - 1);
                float4* t = min_; min_ = mout_; mout_ = t;
            }
        }
    } else {
        // fallback: atomic scatter path (needs 48B/node)
        float4* E0  = (float4*)(ws);
        float4* mu  = (float4*)(ws + (size_t)N * 16);
        float4* acc = (float4*)(ws + (size_t)N * 32);
        const int EB = 256, NB = 256;
        const int EG = (E + EB - 1) / EB;
        const int NG = (N + NB - 1) / NB;
        hipMemsetAsync(E0, 0, (size_t)N * 16, stream);
        fb_e0_kernel<<<EG, EB, 0, stream>>>(esrc, edst, dist, vec, pol, chg, E0, E);
        fb_init_kernel<<<NG, NB, 0, stream>>>(pol, E0, mu, acc, N);
        for (int it = 0; it < NITER; ++it) {
            fb_matvec_kernel<<<EG, EB, 0, stream>>>(esrc, edst, dist, vec, pol, mu, acc, E);
            fb_update_kernel<<<NG, NB, 0, stream>>>(pol, E0, acc, mu, out, N, it == NITER - 1);
        }
    }
}